// Round 7
// baseline (193.599 us; speedup 1.0000x reference)
//
#include <hip/hip_runtime.h>
#include <stdint.h>

#define Bb 32
#define Nn 256
#define Ee 8
#define Ff 16
#define K1 32

typedef unsigned long long u64;
typedef float f32x4 __attribute__((ext_vector_type(4)));

// Kernel AB: fused bitmask-pack + BFS. One block per batch (32 x 256).
// Phase 1: wave-ballot pack adjacency -> 256-bit row masks in LDS.
// Phase 2: per-thread BFS (start = t), queues in LDS (never scratch).
// Writes bm (for C's bmrow gathers) and proc32.
__global__ void ab_kernel(const float* __restrict__ adj,
                          u64* __restrict__ bm_g, uint32_t* __restrict__ proc32) {
    __shared__ u64 bml[Nn * 4];          // 8 KB [row][word]
    __shared__ uint8_t order[Nn * K1];   // 8 KB
    int b = blockIdx.x;
    int t = threadIdx.x;
    int w = t >> 6, l = t & 63;
    const float* base = adj + (size_t)b * Nn * Nn;

    // pack: wave w handles rows [w*64, w*64+64)
    for (int rr = 0; rr < 64; ++rr) {
        int row = (w << 6) + rr;
#pragma unroll
        for (int seg = 0; seg < 4; ++seg) {
            float v = base[row * 256 + seg * 64 + l];
            u64 m = __ballot(v != 0.0f);
            if (l == 0) bml[row * 4 + seg] = m;
        }
    }
    __syncthreads();

    // BFS for start vertex s = t (matches reference FIFO order)
    int s = t;
    u64 seen[4];
#pragma unroll
    for (int q = 0; q < 4; ++q) seen[q] = (q == (s >> 6)) ? (1ull << (s & 63)) : 0ull;
    order[s * K1] = (uint8_t)s;
    int count = 1;
    for (int i = 0; i < count && count < K1; ++i) {
        int cur = order[s * K1 + i];
#pragma unroll
        for (int q = 0; q < 4; ++q) {
            u64 nw = bml[cur * 4 + q] & ~seen[q];
            seen[q] |= nw;   // extras past 32 harmless (never dequeued)
            while (nw) {
                int bit = __builtin_ctzll(nw);
                nw &= nw - 1;
                if (count < K1) order[s * K1 + count++] = (uint8_t)(q * 64 + bit);
                else break;
            }
        }
    }
    __syncthreads();
#pragma unroll
    for (int k = 0; k < 4; ++k) bm_g[(size_t)b * 1024 + t + k * 256] = bml[t + k * 256];
    const uint32_t* ord32 = (const uint32_t*)order;
#pragma unroll
    for (int k = 0; k < 8; ++k)
        proc32[(size_t)b * 2048 + t + k * 256] = ord32[t + k * 256];
}

// Kernel C: 2048 blocks x 256 threads; each block = 4 consecutive bs of one
// batch, on one XCD (swizzled). Batched 2-barrier prologue, then 4x pure
// compute+store (156 KB contiguous-ish store stream per block).
__global__ void gather4_kernel(const f32x4* __restrict__ e4,
                               const f32x4* __restrict__ feats4,
                               const u64* __restrict__ bm,
                               const uint32_t* __restrict__ proc32,
                               float* __restrict__ out) {
    int n = blockIdx.x;
    int bs0 = ((n & 7) << 10) | ((n >> 3) << 2);   // bijective, XCD-chunked
    int b = bs0 >> 8;
    int t = threadIdx.x;
    __shared__ uint8_t p4[4][K1];
    __shared__ u64 bm4[4][K1][4];

    if (t < 32) {
        int c = t >> 3, wd = t & 7;
        uint32_t w = proc32[(size_t)(bs0 + c) * 8 + wd];
        p4[c][wd * 4 + 0] = w & 255;
        p4[c][wd * 4 + 1] = (w >> 8) & 255;
        p4[c][wd * 4 + 2] = (w >> 16) & 255;
        p4[c][wd * 4 + 3] = (w >> 24) & 255;
    }
    __syncthreads();
#pragma unroll
    for (int h = 0; h < 2; ++h) {
        int f = t + h * 256;                      // 512 words total
        int c = f >> 7, i = (f >> 2) & 31, wd = f & 3;
        bm4[c][i][wd] = bm[((size_t)b * 256 + p4[c][i]) * 4 + wd];
    }
    __syncthreads();

#pragma unroll
    for (int c = 0; c < 4; ++c) {
        int bs = bs0 + c;

        // ---- sub_adj ----
        f32x4* out0 = (f32x4*)out + (size_t)bs * 256;
        {
            int i = t >> 3;
            int j0 = (t & 7) * 4;
            f32x4 a;
            int pj;
            pj = p4[c][j0 + 0]; a.x = (float)((bm4[c][i][pj >> 6] >> (pj & 63)) & 1ull);
            pj = p4[c][j0 + 1]; a.y = (float)((bm4[c][i][pj >> 6] >> (pj & 63)) & 1ull);
            pj = p4[c][j0 + 2]; a.z = (float)((bm4[c][i][pj >> 6] >> (pj & 63)) & 1ull);
            pj = p4[c][j0 + 3]; a.w = (float)((bm4[c][i][pj >> 6] >> (pj & 63)) & 1ull);
            out0[t] = a;
        }

        // ---- sub_feats ----
        f32x4* out2 = (f32x4*)(out + 75497472ull) + (size_t)bs * 128;
        if (t < 128) {
            int i = t >> 2, f4 = t & 3;
            out2[t] = feats4[((size_t)b * 256 + p4[c][i]) * 4 + f4];
        }

        // ---- sub_edges ----
        f32x4* out1 = (f32x4*)(out + 8388608ull) + (size_t)bs * 2048;
#pragma unroll
        for (int k = 0; k < 8; ++k) {
            int v = t + k * 256;
            int i = v >> 6, j = (v >> 1) & 31, h = v & 1;
            int pi = p4[c][i], pj = p4[c][j];
            bool m = (bm4[c][i][pj >> 6] >> (pj & 63)) & 1ull;
            f32x4 val = (f32x4){0.f, 0.f, 0.f, 0.f};
            if (m) val = e4[(((size_t)b * 256 + pi) * 256 + pj) * 2 + h];
            out1[v] = val;
        }
    }
}

extern "C" void kernel_launch(void* const* d_in, const int* in_sizes, int n_in,
                              void* d_out, int out_size, void* d_ws, size_t ws_size,
                              hipStream_t stream) {
    const float* adj   = (const float*)d_in[0];
    const float* edges = (const float*)d_in[1];
    const float* feats = (const float*)d_in[2];
    float* out = (float*)d_out;

    u64* bm = (u64*)d_ws;                                          // 262144 B
    uint32_t* proc32 = (uint32_t*)((char*)d_ws + (size_t)Bb * Nn * 4 * sizeof(u64));

    ab_kernel<<<Bb, 256, 0, stream>>>(adj, bm, proc32);
    gather4_kernel<<<2048, 256, 0, stream>>>((const f32x4*)edges, (const f32x4*)feats,
                                             bm, proc32, out);
}

// Round 8
// 81.802 us; speedup vs baseline: 2.3667x; 2.3667x over previous
//
#include <hip/hip_runtime.h>
#include <stdint.h>

#define Bb 32
#define Nn 256
#define Ee 8
#define Ff 16
#define K1 32

typedef unsigned long long u64;
typedef float f32x4 __attribute__((ext_vector_type(4)));

// Kernel A: adjacency floats -> 256-bit row bitmasks. One wave per (b,r).
__global__ void bitmask_kernel(const float* __restrict__ adj, u64* __restrict__ bm) {
    int wave = (blockIdx.x << 2) + (threadIdx.x >> 6);   // (b*N + r), 4 waves/block
    int lane = threadIdx.x & 63;
    const float* row = adj + (size_t)wave * Nn;
#pragma unroll
    for (int w = 0; w < 4; ++w) {
        float v = row[w * 64 + lane];
        u64 m = __ballot(v != 0.0f);
        if (lane == 0) bm[(size_t)wave * 4 + w] = m;
    }
}

// Kernel B2: wave-parallel BFS, one WAVE per start vertex. 2048 blocks x 256.
// Branch-free enqueue: position = count + popc(prefix bits). Also emits the
// 32x32 submask per start (16 ballots) so kernel C needs no scattered gathers.
__global__ void bfs2_kernel(const u64* __restrict__ bm,
                            uint32_t* __restrict__ proc32,
                            uint32_t* __restrict__ submask_g) {
    __shared__ u64 bml[Nn * 4];              // 8 KB: batch bitmask rows
    __shared__ uint8_t order[4][K1];         // per-wave BFS queue
    __shared__ uint32_t subm[4][K1];         // per-wave 32x32 submask
    int blk = blockIdx.x;
    int b = blk >> 6;                        // 64 blocks per batch
    int t = threadIdx.x;
    int wv = t >> 6, l = t & 63;

#pragma unroll
    for (int k = 0; k < 4; ++k) bml[t + k * 256] = bm[(size_t)b * 1024 + t + k * 256];
    __syncthreads();

    int s = ((blk & 63) << 2) + wv;          // this wave's start vertex
    u64 seen[4];
#pragma unroll
    for (int q = 0; q < 4; ++q) seen[q] = (q == (s >> 6)) ? (1ull << (s & 63)) : 0ull;
    if (l == 0) order[wv][0] = (uint8_t)s;
    u64 lpre = (1ull << l) - 1ull;           // prefix mask for this lane
    int count = 1;                           // wave-uniform
    for (int i = 0; i < K1; ++i) {
        int cur = order[wv][i];              // uniform LDS read (same wave wrote it)
#pragma unroll
        for (int q = 0; q < 4; ++q) {
            u64 nw = bml[cur * 4 + q] & ~seen[q];
            seen[q] |= nw;
            int pos = count + __popcll(nw & lpre);
            if (((nw >> l) & 1ull) && pos < K1)
                order[wv][pos] = (uint8_t)((q << 6) + l);
            count += __popcll(nw);           // uniform
        }
        if (count >= K1) break;              // order[0..31] is final
    }

    // 32x32 submask: 16 ballot steps, 2 rows per step (lanes 0-31 / 32-63)
    int half = l >> 5, j2 = l & 31;
#pragma unroll
    for (int step = 0; step < 16; ++step) {
        int row = order[wv][step * 2 + half];
        int pj = order[wv][j2];
        bool bit = (bml[row * 4 + (pj >> 6)] >> (pj & 63)) & 1ull;
        u64 bal = __ballot(bit);
        if (l == 0)  subm[wv][step * 2]     = (uint32_t)bal;
        if (l == 32) subm[wv][step * 2 + 1] = (uint32_t)(bal >> 32);
    }

    // coalesced writeout
    const uint32_t* o32 = (const uint32_t*)&order[wv][0];
    if (l < 8) proc32[((size_t)b * 256 + s) * 8 + l] = o32[l];
    if (l < 32) submask_g[((size_t)b * 256 + s) * 32 + l] = subm[wv][l];
}

// Kernel C: gather all three outputs. One block per (b,s). R1-simple form
// (every added complexity measured slower); prologue is 160 B coalesced.
__global__ void gather_kernel(const f32x4* __restrict__ e4,
                              const f32x4* __restrict__ feats4,
                              const uint32_t* __restrict__ proc32,
                              const uint32_t* __restrict__ submask_g,
                              float* __restrict__ out) {
    int bs = blockIdx.x;
    int b = bs >> 8;
    int t = threadIdx.x;
    __shared__ int p[K1];
    __shared__ uint32_t sm[K1];

    if (t < 8) {
        uint32_t w = proc32[(size_t)bs * 8 + t];
        p[t * 4 + 0] = w & 255;
        p[t * 4 + 1] = (w >> 8) & 255;
        p[t * 4 + 2] = (w >> 16) & 255;
        p[t * 4 + 3] = (w >> 24) & 255;
    }
    if (t >= 64 && t < 96) sm[t - 64] = submask_g[(size_t)bs * 32 + (t - 64)];
    __syncthreads();

    // ---- sub_adj: (K1,K1) floats, 256 f32x4 per block ----
    f32x4* out0 = (f32x4*)(out) + (size_t)bs * 256;
    {
        int i = t >> 3;
        int j0 = (t & 7) * 4;
        uint32_t m = sm[i];
        f32x4 a;
        a.x = (float)((m >> (j0 + 0)) & 1u);
        a.y = (float)((m >> (j0 + 1)) & 1u);
        a.z = (float)((m >> (j0 + 2)) & 1u);
        a.w = (float)((m >> (j0 + 3)) & 1u);
        out0[t] = a;
    }

    // ---- sub_feats: (K1,F) floats, 128 f32x4 per block ----
    f32x4* out2 = (f32x4*)(out + 75497472ull) + (size_t)bs * 128;
    if (t < 128) {
        int i = t >> 2, f4 = t & 3;
        out2[t] = feats4[((size_t)b * 256 + p[i]) * 4 + f4];
    }

    // ---- sub_edges: (K1,K1,E) floats, 2048 f32x4 per block ----
    f32x4* out1 = (f32x4*)(out + 8388608ull) + (size_t)bs * 2048;
#pragma unroll
    for (int k = 0; k < 8; ++k) {
        int v = t + k * 256;
        int i = v >> 6, j = (v >> 1) & 31, h = v & 1;
        bool m = (sm[i] >> j) & 1u;
        f32x4 val = (f32x4){0.f, 0.f, 0.f, 0.f};
        if (m) val = e4[(((size_t)b * 256 + p[i]) * 256 + p[j]) * 2 + h];
        out1[v] = val;
    }
}

extern "C" void kernel_launch(void* const* d_in, const int* in_sizes, int n_in,
                              void* d_out, int out_size, void* d_ws, size_t ws_size,
                              hipStream_t stream) {
    const float* adj   = (const float*)d_in[0];
    const float* edges = (const float*)d_in[1];
    const float* feats = (const float*)d_in[2];
    float* out = (float*)d_out;

    u64* bm = (u64*)d_ws;                                       // 256 KB
    uint32_t* proc32  = (uint32_t*)((char*)d_ws + (256 << 10)); // 256 KB
    uint32_t* submask = (uint32_t*)((char*)d_ws + (512 << 10)); // 1 MB

    bitmask_kernel<<<Bb * Nn / 4, 256, 0, stream>>>(adj, bm);
    bfs2_kernel<<<2048, 256, 0, stream>>>(bm, proc32, submask);
    gather_kernel<<<Bb * Nn, 256, 0, stream>>>((const f32x4*)edges, (const f32x4*)feats,
                                               proc32, submask, out);
}